// Round 6
// baseline (181.944 us; speedup 1.0000x reference)
//
#include <hip/hip_runtime.h>
#include <stdint.h>

#define BINS    64
#define THREADS 128
#define CHUNKS  64                // blocks per channel-image
#define NPIX    (512*512)
#define PPB     (NPIX / CHUNKS)   // 4096 pixels per block
#define ITERS   (PPB / 4 / THREADS)
#define NCH     12                // 4*3 channel-images per input

// ---------------- atomic (fire-and-forget ds_add_f32) variant --------------
#define STR_A   73                // dwords per column; gcd(73,32)=1 -> full bank spread

__global__ __launch_bounds__(THREADS) void hist_atomic(
    const float* __restrict__ src_base, float* __restrict__ part)
{
    __shared__ float lh[THREADS * STR_A];   // 37376 B
    const int tid = threadIdx.x;
    for (int i = tid; i < THREADS * STR_A; i += THREADS) lh[i] = 0.0f;
    __syncthreads();

    const int chunk = blockIdx.x;
    const int ch    = blockIdx.y;
    const float* src = src_base + (size_t)ch * NPIX + (size_t)chunk * PPB;
    const float4* src4 = (const float4*)src;

    const float C1 = 0.60653065971e0f;
    const float C2 = 0.13533528324e0f;
    const float C3 = 1.11089965382e-2f;
    const float C4 = 3.35462627903e-4f;
    const float C5 = 3.72665317208e-6f;

    float* col = &lh[tid * STR_A];

    #pragma unroll
    for (int k = 0; k < ITERS; ++k) {
        float4 v = src4[(size_t)k * THREADS + tid];
        float xv[4] = {v.x, v.y, v.z, v.w};
        #pragma unroll
        for (int e = 0; e < 4; ++e) {
            float xs = xv[e] * 64.0f;            // [0, 64)
            float fp = floorf(xs * 0.5f);        // pair index P: 0..31
            int   P  = (int)fp;
            float d  = xs - 2.0f * fp - 0.5f;    // [-0.5, 1.5)
            float t0 = __expf(-0.5f * d * d);
            float g  = __expf(d);
            float gi = __expf(-d);
            float t1 = t0 * C1, t2 = t0 * C2, t3 = t0 * C3;
            float t4 = t0 * C4, t5 = t0 * C5;
            float g2 = g * g,  g3 = g2 * g,  g4 = g2 * g2, g5 = g3 * g2;
            float h2 = gi * gi, h3 = h2 * gi, h4 = h2 * h2;
            // bins 2P+m, m=-4..5 ; dword = 2P+m+4 ; base dword = 2P
            float* c = col + 2 * P;
            atomicAdd(c + 0, t4 * h4);   // m=-4
            atomicAdd(c + 1, t3 * h3);
            atomicAdd(c + 2, t2 * h2);
            atomicAdd(c + 3, t1 * gi);
            atomicAdd(c + 4, t0);        // m=0
            atomicAdd(c + 5, t1 * g);
            atomicAdd(c + 6, t2 * g2);
            atomicAdd(c + 7, t3 * g3);
            atomicAdd(c + 8, t4 * g4);
            atomicAdd(c + 9, t5 * g5);   // m=+5
        }
    }
    __syncthreads();

    // bin b lives at dword (b + 4) of each 73-dword column
    const int bin = tid & 63;
    const int h   = tid >> 6;
    float s = 0.0f;
    #pragma unroll 8
    for (int i = 0; i < 64; ++i)
        s += lh[(h * 64 + i) * STR_A + bin + 4];
    __syncthreads();                 // all reads done before scratch overwrite
    lh[tid * STR_A + 72] = s;        // dword 72 (bin 68) never deposited
    __syncthreads();

    if (tid < 64) {
        float tot = lh[tid * STR_A + 72] + lh[(tid + 64) * STR_A + 72];
        part[(((size_t)0 * NCH + ch) * CHUNKS + chunk) * BINS + tid] = tot;
    }
}

// ---------------- RMW b128 variant (R5 scheme, unchanged) ------------------
#define NF4     19
#define STRIDE  76

__global__ __launch_bounds__(THREADS) void hist_rmw(
    const float* __restrict__ src_base, float* __restrict__ part)
{
    __shared__ float4 lh4[THREADS * NF4];   // 38912 B
    const int tid = threadIdx.x;

    float4* base = &lh4[tid * NF4];
    #pragma unroll
    for (int i = 0; i < NF4; ++i) base[i] = make_float4(0.f, 0.f, 0.f, 0.f);
    __syncthreads();

    const int chunk = blockIdx.x;
    const int ch    = blockIdx.y;
    const float* src = src_base + (size_t)ch * NPIX + (size_t)chunk * PPB;
    const float4* src4 = (const float4*)src;

    const float C1 = 0.60653065971e0f;
    const float C2 = 0.13533528324e0f;
    const float C3 = 1.11089965382e-2f;
    const float C4 = 3.35462627903e-4f;
    const float C5 = 3.72665317208e-6f;
    const float C6 = 1.52299797447e-8f;

    #pragma unroll
    for (int k = 0; k < ITERS; ++k) {
        float4 v = src4[(size_t)k * THREADS + tid];
        float xv[4] = {v.x, v.y, v.z, v.w};
        #pragma unroll
        for (int e = 0; e < 4; ++e) {
            float xs = xv[e] * 64.0f;
            float fq = floorf(xs * 0.25f);
            int   Q  = (int)fq;
            float d0 = xs - 4.0f * fq - 1.5f;    // [-1.5, 2.5)
            float t0 = __expf(-0.5f * d0 * d0);
            float g  = __expf(d0);
            float gi = __expf(-d0);
            float t1 = t0 * C1, t2 = t0 * C2, t3 = t0 * C3;
            float t4 = t0 * C4, t5 = t0 * C5, t6 = t0 * C6;
            float g2 = g * g,   g3 = g2 * g,  g4 = g2 * g2;
            float g5 = g3 * g2, g6 = g3 * g3;
            float h2 = gi * gi, h3 = h2 * gi, h4 = h2 * h2, h5 = h3 * h2;
            float4* c = base + Q;
            float4 a0 = c[0], a1 = c[1], a2 = c[2];
            a0.x += t5 * h5; a0.y += t4 * h4; a0.z += t3 * h3; a0.w += t2 * h2;
            a1.x += t1 * gi; a1.y += t0;      a1.z += t1 * g;  a1.w += t2 * g2;
            a2.x += t3 * g3; a2.y += t4 * g4; a2.z += t5 * g5; a2.w += t6 * g6;
            c[0] = a0; c[1] = a1; c[2] = a2;
        }
    }
    __syncthreads();

    const float* lhf = (const float*)lh4;
    float* lhw = (float*)lh4;
    const int bin = tid & 63;
    const int h   = tid >> 6;
    float s = 0.0f;
    #pragma unroll 8
    for (int i = 0; i < 64; ++i)
        s += lhf[(h * 64 + i) * STRIDE + bin + 4];
    __syncthreads();
    lhw[tid * STRIDE + 72] = s;
    __syncthreads();

    if (tid < 64) {
        float tot = lhf[tid * STRIDE + 72] + lhf[(tid + 64) * STRIDE + 72];
        part[(((size_t)1 * NCH + ch) * CHUNKS + chunk) * BINS + tid] = tot;
    }
}

// ---------------- reduction + finalize -------------------------------------
__global__ __launch_bounds__(64) void reduce_kernel(
    const float* __restrict__ part, float* __restrict__ chist /* [24][BINS] */)
{
    const int ci  = blockIdx.x;
    const int bin = threadIdx.x;
    float s = 0.0f;
    #pragma unroll 16
    for (int i = 0; i < CHUNKS; ++i)
        s += part[((size_t)ci * CHUNKS + i) * BINS + bin];
    chist[ci * BINS + bin] = s;
}

__global__ __launch_bounds__(256) void finalize_kernel(
    const float* __restrict__ chist, float* __restrict__ out)
{
    __shared__ float wsum[4];
    const int tid  = threadIdx.x;
    const int lane = tid & 63;
    const int w    = tid >> 6;
    float acc = 0.0f;
    for (int c = w * 3; c < w * 3 + 3; ++c) {
        float cp = chist[c * BINS + lane];
        float ct = chist[(NCH + c) * BINS + lane];
        #pragma unroll
        for (int off = 1; off < 64; off <<= 1) {
            float a = __shfl_up(cp, off, 64);
            float b = __shfl_up(ct, off, 64);
            if (lane >= off) { cp += a; ct += b; }
        }
        float sp = __shfl(cp, 63, 64);
        float st = __shfl(ct, 63, 64);
        float diff = fabsf(cp / (sp + 1e-8f) - ct / (st + 1e-8f));
        #pragma unroll
        for (int off = 32; off; off >>= 1)
            diff += __shfl_xor(diff, off, 64);
        acc += diff;
    }
    if (lane == 0) wsum[w] = acc;
    __syncthreads();
    if (tid == 0)
        out[0] = (wsum[0] + wsum[1] + wsum[2] + wsum[3]) / (float)(NCH * BINS);
}

extern "C" void kernel_launch(void* const* d_in, const int* in_sizes, int n_in,
                              void* d_out, int out_size, void* d_ws, size_t ws_size,
                              hipStream_t stream)
{
    const float* pred   = (const float*)d_in[0];
    const float* target = (const float*)d_in[1];
    float* part  = (float*)d_ws;                   // 2*12*64*64 floats
    float* chist = part + 2 * NCH * CHUNKS * BINS; // 24*64 floats

    hist_atomic<<<dim3(CHUNKS, NCH, 1), THREADS, 0, stream>>>(pred, part);
    hist_rmw   <<<dim3(CHUNKS, NCH, 1), THREADS, 0, stream>>>(target, part);
    reduce_kernel<<<2 * NCH, 64, 0, stream>>>(part, chist);
    finalize_kernel<<<1, 256, 0, stream>>>(chist, (float*)d_out);
}

// Round 7
// 27.489 us; speedup vs baseline: 6.6187x; 6.6187x over previous
//
#include <hip/hip_runtime.h>
#include <hip/hip_fp16.h>
#include <stdint.h>

#define BINS    64
#define STRIDE  38                // dwords per column (36 used + 2 pad); even -> b64 aligned
#define THREADS 128
#define CHUNKS  64                // blocks per channel-image
#define NPIX    (512*512)
#define PPB     (NPIX / CHUNKS)   // 4096 pixels per block
#define ITERS   (PPB / 4 / THREADS)
#define NCH     12                // 4*3 channel-images per input

__device__ __forceinline__ uint32_t h2add(uint32_t u, __half2 w) {
    __half2 v = *(__half2*)&u;
    v = __hadd2(v, w);
    return *(uint32_t*)&v;
}

__global__ __launch_bounds__(THREADS) void hist_kernel(
    const float* __restrict__ pred, const float* __restrict__ target,
    float* __restrict__ part /* [2][NCH][CHUNKS][BINS] */)
{
    __shared__ float lh[THREADS * STRIDE];   // 19456 B -> 8 blocks/CU capacity
    const int tid = threadIdx.x;

    uint2* col2 = (uint2*)&lh[tid * STRIDE];   // 19 uint2 slots, 8B aligned
    #pragma unroll
    for (int i = 0; i < STRIDE / 2; ++i) col2[i] = make_uint2(0u, 0u);
    __syncthreads();

    const int chunk = blockIdx.x;
    const int ch    = blockIdx.y;
    const int z     = blockIdx.z;
    const float* src = (z == 0 ? pred : target)
                     + (size_t)ch * NPIX + (size_t)chunk * PPB;
    const float4* src4 = (const float4*)src;

    // C_k = exp(-k*k/2)
    const float C1 = 0.60653065971e0f;
    const float C2 = 0.13533528324e0f;
    const float C3 = 1.11089965382e-2f;
    const float C4 = 3.35462627903e-4f;
    const float C5 = 3.72665317208e-6f;
    const float C6 = 1.52299797447e-8f;

    float4 v = src4[tid];
    #pragma unroll
    for (int k = 0; k < ITERS; ++k) {
        float4 vn = (k + 1 < ITERS) ? src4[(size_t)(k + 1) * THREADS + tid]
                                    : make_float4(0.f, 0.f, 0.f, 0.f);
        float xv[4] = {v.x, v.y, v.z, v.w};
        #pragma unroll
        for (int e = 0; e < 4; ++e) {
            float xs = xv[e] * 64.0f;            // [0, 64)
            float fq = floorf(xs * 0.25f);       // quad index Q: 0..15
            int   Q  = (int)fq;
            float d0 = xs - 4.0f * fq - 1.5f;    // [-1.5, 2.5)
            float t0 = __expf(-0.5f * d0 * d0);
            float g  = __expf(d0);
            float gi = __expf(-d0);
            // bins 4Q+o, o=-4..7 ; k=o-1 in -5..6 ; w_k = t0*C_|k|*g^k
            float t1 = t0 * C1, t2 = t0 * C2, t3 = t0 * C3;
            float t4 = t0 * C4, t5 = t0 * C5, t6 = t0 * C6;
            float g2 = g * g,   g3 = g2 * g,  g4 = g2 * g2;
            float g5 = g3 * g2, g6 = g3 * g3;
            float h2 = gi * gi, h3 = h2 * gi, h4 = h2 * h2, h5 = h3 * h2;
            // packed dword j covers bins {2j, 2j+1}; window j = 2Q-2 .. 2Q+3
            __half2 w0 = __floats2half2_rn(t5 * h5, t4 * h4);  // bins 4Q-4,4Q-3
            __half2 w1 = __floats2half2_rn(t3 * h3, t2 * h2);  // 4Q-2,4Q-1
            __half2 w2 = __floats2half2_rn(t1 * gi, t0);       // 4Q  ,4Q+1
            __half2 w3 = __floats2half2_rn(t1 * g,  t2 * g2);  // 4Q+2,4Q+3
            __half2 w4 = __floats2half2_rn(t3 * g3, t4 * g4);  // 4Q+4,4Q+5
            __half2 w5 = __floats2half2_rn(t5 * g5, t6 * g6);  // 4Q+6,4Q+7
            uint2* c = col2 + Q;       // storage dword s = j+2 -> uint2 idx Q
            uint2 a0 = c[0], a1 = c[1], a2 = c[2];
            a0.x = h2add(a0.x, w0); a0.y = h2add(a0.y, w1);
            a1.x = h2add(a1.x, w2); a1.y = h2add(a1.y, w3);
            a2.x = h2add(a2.x, w4); a2.y = h2add(a2.y, w5);
            c[0] = a0; c[1] = a1; c[2] = a2;
        }
        v = vn;
    }
    __syncthreads();

    // bin b lives at packed dword (b>>1)+2, half (b&1), of each column
    const int bin = tid & 63;
    const int h   = tid >> 6;
    const int sd  = (bin >> 1) + 2;
    float s = 0.0f;
    #pragma unroll 8
    for (int i = 0; i < 64; ++i) {
        uint32_t u = *(const uint32_t*)&lh[(h * 64 + i) * STRIDE + sd];
        __half2 hv = *(__half2*)&u;
        s += (bin & 1) ? __high2float(hv) : __low2float(hv);
    }
    __syncthreads();                 // all reads done before scratch overwrite
    lh[tid * STRIDE + 36] = s;       // pad dword as f32 scratch
    __syncthreads();

    if (tid < 64) {
        float tot = lh[tid * STRIDE + 36] + lh[(tid + 64) * STRIDE + 36];
        part[(((size_t)z * NCH + ch) * CHUNKS + chunk) * BINS + tid] = tot;
    }
}

// Fold chunk partials: 24 blocks (one per channel-image), 64 threads (bin).
__global__ __launch_bounds__(64) void reduce_kernel(
    const float* __restrict__ part, float* __restrict__ chist /* [24][BINS] */)
{
    const int ci  = blockIdx.x;
    const int bin = threadIdx.x;
    float s = 0.0f;
    #pragma unroll 16
    for (int i = 0; i < CHUNKS; ++i)
        s += part[((size_t)ci * CHUNKS + i) * BINS + bin];
    chist[ci * BINS + bin] = s;
}

__global__ __launch_bounds__(256) void finalize_kernel(
    const float* __restrict__ chist, float* __restrict__ out)
{
    __shared__ float wsum[4];
    const int tid  = threadIdx.x;
    const int lane = tid & 63;          // lane == bin
    const int w    = tid >> 6;          // wave id 0..3, handles 3 channels
    float acc = 0.0f;
    for (int c = w * 3; c < w * 3 + 3; ++c) {
        float cp = chist[c * BINS + lane];
        float ct = chist[(NCH + c) * BINS + lane];
        #pragma unroll
        for (int off = 1; off < 64; off <<= 1) {
            float a = __shfl_up(cp, off, 64);
            float b = __shfl_up(ct, off, 64);
            if (lane >= off) { cp += a; ct += b; }
        }
        float sp = __shfl(cp, 63, 64);
        float st = __shfl(ct, 63, 64);
        float diff = fabsf(cp / (sp + 1e-8f) - ct / (st + 1e-8f));
        #pragma unroll
        for (int off = 32; off; off >>= 1)
            diff += __shfl_xor(diff, off, 64);
        acc += diff;
    }
    if (lane == 0) wsum[w] = acc;
    __syncthreads();
    if (tid == 0)
        out[0] = (wsum[0] + wsum[1] + wsum[2] + wsum[3]) / (float)(NCH * BINS);
}

extern "C" void kernel_launch(void* const* d_in, const int* in_sizes, int n_in,
                              void* d_out, int out_size, void* d_ws, size_t ws_size,
                              hipStream_t stream)
{
    const float* pred   = (const float*)d_in[0];
    const float* target = (const float*)d_in[1];
    float* part  = (float*)d_ws;                   // 2*12*64*64 floats
    float* chist = part + 2 * NCH * CHUNKS * BINS; // 24*64 floats

    hist_kernel<<<dim3(CHUNKS, NCH, 2), THREADS, 0, stream>>>(pred, target, part);
    reduce_kernel<<<2 * NCH, 64, 0, stream>>>(part, chist);
    finalize_kernel<<<1, 256, 0, stream>>>(chist, (float*)d_out);
}